// Round 7
// baseline (243.082 us; speedup 1.0000x reference)
//
#include <hip/hip_runtime.h>

// SSIM, fused: reflect-pad(1) + five 3x3 box filters + elementwise formula.
// NCHW 32x3x384x640 fp32.
//
// v8: copy-pattern global access + LDS halo redistribution.
// Evidence: v1..v7 all pin at 90-103us / 2.5-2.9 TB/s across 6x VMEM-count,
// 1.6x VALU, 4x concurrency changes -> fixed per-byte cost in the memory path
// (scattered 512B-wide column-strip bursts + 2x overlapped lane reads), not
// occupancy/ILP. v8 stages FULL 640-wide rows per 5-wave block: one disjoint
// aligned dwordx4 per thread per array covers TWO rows (5120B contiguous per
// array per step, the m13 6.3TB/s pattern), swept down a 24-row strip.
// Halo taps come from LDS (reflect pre-materialized in tail slots).
//  - Register rolling 3-row window + 81^2-scaled SSIM + rcp + NT stores kept.
//  - Double-buffered LDS (20.6KB); raw s_barrier + lgkmcnt(0) only (prefetch
//    for step s+2 stays in flight across barriers - never vmcnt(0)).
//  - grid (1,16,96)=1536 blocks = exactly 6 blocks/CU resident, zero tail.

constexpr int HH = 384;
constexpr int WW = 640;
constexpr int THREADS = 320;        // 5 waves; 320*4 floats = 2 full rows
constexpr int HS = 24;              // output rows per block strip
constexpr int LROW = 644;           // 640 + 2 halo slots + pad (16B row align)
constexpr float C1 = 0.01f * 0.01f;
constexpr float C2 = 0.03f * 0.03f;
constexpr float K1 = 81.0f * C1;    // 0.0081f
constexpr float K2 = 81.0f * C2;    // 0.0729f

typedef float f32x4 __attribute__((ext_vector_type(4)));
typedef float f32x2 __attribute__((ext_vector_type(2)));

__global__ __launch_bounds__(THREADS) void ssim_kernel(
    const float* __restrict__ x, const float* __restrict__ y,
    float* __restrict__ out)
{
    // [buf][array(x,y)][pair-row][col]; halo: [640]=reflect-left, [641]=reflect-right
    __shared__ __align__(16) float lds[2][2][2][LROW];

    const int t  = threadIdx.x;
    const int h0 = blockIdx.y * HS;
    const size_t pbase = (size_t)blockIdx.z * (size_t)(HH * WW);
    const float* __restrict__ xp = x + pbase;
    const float* __restrict__ yp = y + pbase;
    float* __restrict__ op = out + pbase;

    // LDS tap indices for this thread's 2 output cols (2t, 2t+1):
    // taps are cols [2t-1 .. 2t+2]; col -1 -> halo[640], col 640 -> halo[641]
    const int i0h = (t == 0)           ? 640 : (2 * t - 1);
    const int i3h = (t == THREADS - 1) ? 641 : (2 * t + 2);

    // rolling 3-row window of horizontal 3-tap sums, 2 cols. Literal indices.
    float hx[3][2], hy[3][2], hxx[3][2], hyy[3][2], hxy[3][2];
    f32x4 rgx0, rgy0, rgx1, rgy1;     // staged row-pairs in flight (2 steps)

    // Step S stages input rows (h0+2S-1, h0+2S); reflect row clamp is
    // block-uniform. Threads t<160 hold row A, t>=160 row B; disjoint 16B/lane.
#define GLOAD(S, RX, RY) do {                                            \
        int ra_ = 2 * (S) - 1 + h0;                                      \
        int rb_ = ra_ + 1;                                               \
        ra_ = (ra_ < 0) ? 1 : ra_;                                       \
        rb_ = (rb_ >= HH) ? (HH - 2) : rb_;                              \
        const int off_ = (t < 160) ? (ra_ * WW + 4 * t)                  \
                                   : (rb_ * WW + 4 * (t - 160));         \
        RX = *reinterpret_cast<const f32x4*>(xp + off_);                 \
        RY = *reinterpret_cast<const f32x4*>(yp + off_);                 \
    } while (0)

#define DSWRITE(B, RX, RY) do {                                          \
        const int p_ = (t < 160) ? 0 : 1;                                \
        const int u_ = (t < 160) ? t : (t - 160);                        \
        *reinterpret_cast<f32x4*>(&lds[B][0][p_][4 * u_]) = RX;          \
        *reinterpret_cast<f32x4*>(&lds[B][1][p_][4 * u_]) = RY;          \
        if (u_ == 0)   { lds[B][0][p_][640] = RX.y; lds[B][1][p_][640] = RY.y; } \
        if (u_ == 159) { lds[B][0][p_][641] = RX.z; lds[B][1][p_][641] = RY.z; } \
    } while (0)

#define BARRIER() do {                                                   \
        asm volatile("s_waitcnt lgkmcnt(0)" ::: "memory");               \
        __builtin_amdgcn_s_barrier();                                    \
        __builtin_amdgcn_sched_barrier(0);                               \
    } while (0)

#define HSUMT(J, B, P) do {                                              \
        const f32x2 xm_ = *reinterpret_cast<const f32x2*>(&lds[B][0][P][2 * t]); \
        const f32x2 ym_ = *reinterpret_cast<const f32x2*>(&lds[B][1][P][2 * t]); \
        const float a0 = lds[B][0][P][i0h], a3 = lds[B][0][P][i3h];      \
        const float b0 = lds[B][1][P][i0h], b3 = lds[B][1][P][i3h];      \
        const float a1 = xm_.x, a2 = xm_.y, b1 = ym_.x, b2 = ym_.y;      \
        const float mx  = a1 + a2;                                       \
        const float my  = b1 + b2;                                       \
        const float mxx = __builtin_fmaf(a1, a1, a2 * a2);               \
        const float myy = __builtin_fmaf(b1, b1, b2 * b2);               \
        const float mxy = __builtin_fmaf(a1, b1, a2 * b2);               \
        hx[J][0]  = mx + a0;                     hx[J][1]  = mx + a3;    \
        hy[J][0]  = my + b0;                     hy[J][1]  = my + b3;    \
        hxx[J][0] = __builtin_fmaf(a0, a0, mxx); hxx[J][1] = __builtin_fmaf(a3, a3, mxx); \
        hyy[J][0] = __builtin_fmaf(b0, b0, myy); hyy[J][1] = __builtin_fmaf(b3, b3, myy); \
        hxy[J][0] = __builtin_fmaf(a0, b0, mxy); hxy[J][1] = __builtin_fmaf(a3, b3, mxy); \
    } while (0)

    // SSIM on raw sums (x81^2): num=(2SxSy+81C1)(18Sxy-2SxSy+81C2),
    // den=(Sx^2+Sy^2+81C1)(9(Sxx+Syy)-Sx^2-Sy^2+81C2)
#define EMIT(O) do {                                                     \
        float o_[2];                                                     \
        _Pragma("unroll")                                                \
        for (int c = 0; c < 2; ++c) {                                    \
            const float Sx  = hx[0][c]  + hx[1][c]  + hx[2][c];          \
            const float Sy  = hy[0][c]  + hy[1][c]  + hy[2][c];          \
            const float Sxx = hxx[0][c] + hxx[1][c] + hxx[2][c];         \
            const float Syy = hyy[0][c] + hyy[1][c] + hyy[2][c];         \
            const float Sxy = hxy[0][c] + hxy[1][c] + hxy[2][c];         \
            const float tt   = Sx * Sy;                                  \
            const float pp   = __builtin_fmaf(Sx, Sx, Sy * Sy);          \
            const float qq   = Sxx + Syy;                                \
            const float numA = __builtin_fmaf(2.0f, tt, K1);             \
            const float numB = __builtin_fmaf(-2.0f, tt,                 \
                                   __builtin_fmaf(18.0f, Sxy, K2));      \
            const float denA = pp + K1;                                  \
            const float denB = __builtin_fmaf(9.0f, qq, K2) - pp;        \
            const float s = (numA * numB)                                \
                            * __builtin_amdgcn_rcpf(denA * denB);        \
            o_[c] = fminf(fmaxf(s, 0.0f), 1.0f);                         \
        }                                                                \
        f32x2 ov_; ov_.x = o_[0]; ov_.y = o_[1];                         \
        __builtin_nontemporal_store(                                     \
            ov_, reinterpret_cast<f32x2*>(op + (size_t)(O) * WW + 2 * t)); \
    } while (0)

    // Step s: prefetch step s+2, consume buf[s%2] (2 rows -> 2 outputs),
    // write step s+1's regs to buf[(s+1)%2], barrier. Loads stay in flight
    // across the barrier (only lgkmcnt is drained).
#define STEP(S, SA, SB, B, LRX, LRY, WRX, WRY, DOLOAD, DOWRITE) do {     \
        if (DOLOAD) GLOAD((S) + 2, LRX, LRY);                            \
        HSUMT(SA, B, 0);  EMIT(h0 + 2 * (S) - 2);                        \
        HSUMT(SB, B, 1);  EMIT(h0 + 2 * (S) - 1);                        \
        if (DOWRITE) { DSWRITE((B) ^ 1, WRX, WRY); BARRIER(); }          \
    } while (0)

    // Prologue: stage steps 0,1 (rows h0-1..h0+2), prefetch step 2.
    GLOAD(0, rgx0, rgy0);
    GLOAD(1, rgx1, rgy1);
    DSWRITE(0, rgx0, rgy0);
    BARRIER();
    HSUMT(0, 0, 0);                  // row h0-1 -> slot 0
    HSUMT(1, 0, 1);                  // row h0   -> slot 1
    GLOAD(2, rgx0, rgy0);
    DSWRITE(1, rgx1, rgy1);
    BARRIER();

    STEP( 1, 2, 0, 1, rgx1, rgy1, rgx0, rgy0, true,  true);
    STEP( 2, 1, 2, 0, rgx0, rgy0, rgx1, rgy1, true,  true);
    STEP( 3, 0, 1, 1, rgx1, rgy1, rgx0, rgy0, true,  true);
    STEP( 4, 2, 0, 0, rgx0, rgy0, rgx1, rgy1, true,  true);
    STEP( 5, 1, 2, 1, rgx1, rgy1, rgx0, rgy0, true,  true);
    STEP( 6, 0, 1, 0, rgx0, rgy0, rgx1, rgy1, true,  true);
    STEP( 7, 2, 0, 1, rgx1, rgy1, rgx0, rgy0, true,  true);
    STEP( 8, 1, 2, 0, rgx0, rgy0, rgx1, rgy1, true,  true);
    STEP( 9, 0, 1, 1, rgx1, rgy1, rgx0, rgy0, true,  true);
    STEP(10, 2, 0, 0, rgx0, rgy0, rgx1, rgy1, true,  true);
    STEP(11, 1, 2, 1, rgx1, rgy1, rgx0, rgy0, false, true);
    STEP(12, 0, 1, 0, rgx0, rgy0, rgx1, rgy1, false, false);

#undef GLOAD
#undef DSWRITE
#undef BARRIER
#undef HSUMT
#undef EMIT
#undef STEP
}

extern "C" void kernel_launch(void* const* d_in, const int* in_sizes, int n_in,
                              void* d_out, int out_size, void* d_ws, size_t ws_size,
                              hipStream_t stream) {
    const float* x = (const float*)d_in[0];
    const float* y = (const float*)d_in[1];
    float* out = (float*)d_out;

    const int planes = in_sizes[0] / (HH * WW);     // 32*3 = 96
    dim3 grid(1, HH / HS, planes);                  // (1, 16, 96) = 1536 blocks
    dim3 block(THREADS);                            // 320 = 5 waves
    ssim_kernel<<<grid, block, 0, stream>>>(x, y, out);
}

// Round 8
// 228.583 us; speedup vs baseline: 1.0634x; 1.0634x over previous
//
#include <hip/hip_runtime.h>

// SSIM, fused: reflect-pad(1) + five 3x3 box filters + elementwise formula.
// NCHW 32x3x384x640 fp32.
//
// v9: MLP saturation probe (H_A bw-wall vs H_B latency-bound discriminator).
// Evidence so far: time is invariant to HBM traffic (v7 259MB vs v8 196MB,
// both ~90-100us), to VMEM instruction count (6x range), and to VALU (1.6x
// range). Every passing kernel kept <=4 loads in flight per wave. v9 issues
// ALL 16 dwordx4 loads of a 6-row strip (8 row-pairs x {x,y}, 4KB/lane)
// back-to-back, then consumes in order via compiler-counted vmcnt(N) drains.
//  - No LDS, no barriers (v8's step-barrier chain collapsed occupancy to 28%).
//  - Named f32x4 scalars only -> scratch-proof (v3 lesson).
//  - ~100 VGPR -> 4 waves/SIMD x 16 outstanding = 2.5-4x v7's in-flight bytes.
//  - Keeps: taps [c0-1..c0+2] via one dwordx4, template<EDGE> clones,
//    81^2-scaled SSIM on raw sums, v_rcp_f32, NT f32x2 stores.
// Work: grid (5,32,96) x 2 waves = 30720 waves = 120/CU (v7's proven level).

constexpr int HH = 384;
constexpr int WW = 640;
constexpr int VEC = 2;              // output columns per thread
constexpr int TCOLS = WW / VEC;     // 320 thread-columns per image row
constexpr int KROWS = 6;            // rows per thread; 8 row-loads incl halo
constexpr int WAVES = 2;            // waves per workgroup
constexpr int BW = 64;              // threads per wave
constexpr float C1 = 0.01f * 0.01f;
constexpr float C2 = 0.03f * 0.03f;
constexpr float K1 = 81.0f * C1;    // 0.0081f
constexpr float K2 = 81.0f * C2;    // 0.0729f

typedef float f32x4 __attribute__((ext_vector_type(4)));
typedef float f32x2 __attribute__((ext_vector_type(2)));

template<bool EDGE>
__device__ __forceinline__ void ssim_body(
    const float* __restrict__ xp, const float* __restrict__ yp,
    float* __restrict__ op, int c0, int h0, bool ledge, bool redge)
{
    // one dwordx4 covers taps [c0-1 .. c0+2]; edge lanes re-wire elements
    const int lbase = ledge ? 0 : (redge ? (WW - 4) : (c0 - 1));

    // rolling 3-row window of horizontal 3-tap sums, 2 cols. Literal indices.
    float hx[3][2], hy[3][2], hxx[3][2], hyy[3][2], hxy[3][2];

#define LOADR(R, VX, VY) do {                                            \
        int rr = (R);                                                    \
        rr = (rr < 0) ? 1 : ((rr >= HH) ? (HH - 2) : rr);                \
        const float* __restrict__ xr = xp + (size_t)rr * WW;             \
        const float* __restrict__ yr = yp + (size_t)rr * WW;             \
        VX = *reinterpret_cast<const f32x4*>(xr + lbase);                \
        VY = *reinterpret_cast<const f32x4*>(yr + lbase);                \
    } while (0)

#define HSUMT(J, VX, VY) do {                                            \
        float a0, a1, a2, a3, b0, b1, b2, b3;                            \
        if constexpr (EDGE) {                                            \
            const bool e = ledge || redge;                               \
            a0 = e ? VX.y : VX.x;                                        \
            a1 = ledge ? VX.x : (redge ? VX.z : VX.y);                   \
            a2 = ledge ? VX.y : (redge ? VX.w : VX.z);                   \
            a3 = e ? VX.z : VX.w;                                        \
            b0 = e ? VY.y : VY.x;                                        \
            b1 = ledge ? VY.x : (redge ? VY.z : VY.y);                   \
            b2 = ledge ? VY.y : (redge ? VY.w : VY.z);                   \
            b3 = e ? VY.z : VY.w;                                        \
        } else {                                                         \
            a0 = VX.x; a1 = VX.y; a2 = VX.z; a3 = VX.w;                  \
            b0 = VY.x; b1 = VY.y; b2 = VY.z; b3 = VY.w;                  \
        }                                                                \
        const float mx  = a1 + a2;                                       \
        const float my  = b1 + b2;                                       \
        const float mxx = __builtin_fmaf(a1, a1, a2 * a2);               \
        const float myy = __builtin_fmaf(b1, b1, b2 * b2);               \
        const float mxy = __builtin_fmaf(a1, b1, a2 * b2);               \
        hx[J][0]  = mx + a0;                     hx[J][1]  = mx + a3;    \
        hy[J][0]  = my + b0;                     hy[J][1]  = my + b3;    \
        hxx[J][0] = __builtin_fmaf(a0, a0, mxx); hxx[J][1] = __builtin_fmaf(a3, a3, mxx); \
        hyy[J][0] = __builtin_fmaf(b0, b0, myy); hyy[J][1] = __builtin_fmaf(b3, b3, myy); \
        hxy[J][0] = __builtin_fmaf(a0, b0, mxy); hxy[J][1] = __builtin_fmaf(a3, b3, mxy); \
    } while (0)

    // SSIM on raw sums (x81^2): num=(2SxSy+81C1)(18Sxy-2SxSy+81C2),
    // den=(Sx^2+Sy^2+81C1)(9(Sxx+Syy)-Sx^2-Sy^2+81C2)
#define EMIT(O) do {                                                     \
        float o_[2];                                                     \
        _Pragma("unroll")                                                \
        for (int c = 0; c < 2; ++c) {                                    \
            const float Sx  = hx[0][c]  + hx[1][c]  + hx[2][c];          \
            const float Sy  = hy[0][c]  + hy[1][c]  + hy[2][c];          \
            const float Sxx = hxx[0][c] + hxx[1][c] + hxx[2][c];         \
            const float Syy = hyy[0][c] + hyy[1][c] + hyy[2][c];         \
            const float Sxy = hxy[0][c] + hxy[1][c] + hxy[2][c];         \
            const float tt   = Sx * Sy;                                  \
            const float pp   = __builtin_fmaf(Sx, Sx, Sy * Sy);          \
            const float qq   = Sxx + Syy;                                \
            const float numA = __builtin_fmaf(2.0f, tt, K1);             \
            const float numB = __builtin_fmaf(-2.0f, tt,                 \
                                   __builtin_fmaf(18.0f, Sxy, K2));      \
            const float denA = pp + K1;                                  \
            const float denB = __builtin_fmaf(9.0f, qq, K2) - pp;        \
            const float s = (numA * numB)                                \
                            * __builtin_amdgcn_rcpf(denA * denB);        \
            o_[c] = fminf(fmaxf(s, 0.0f), 1.0f);                         \
        }                                                                \
        f32x2 ov_; ov_.x = o_[0]; ov_.y = o_[1];                         \
        __builtin_nontemporal_store(                                     \
            ov_, reinterpret_cast<f32x2*>(op + (size_t)(O) * WW + c0));  \
    } while (0)

    // All 8 row-pair loads (x,y) issued back-to-back: 16 dwordx4 in flight.
    f32x4 x0, x1, x2, x3, x4, x5, x6, x7;
    f32x4 y0, y1, y2, y3, y4, y5, y6, y7;
    LOADR(h0 - 1, x0, y0);
    LOADR(h0 + 0, x1, y1);
    LOADR(h0 + 1, x2, y2);
    LOADR(h0 + 2, x3, y3);
    LOADR(h0 + 3, x4, y4);
    LOADR(h0 + 4, x5, y5);
    LOADR(h0 + 5, x6, y6);
    LOADR(h0 + 6, x7, y7);

    // Consume in order; compiler emits counted vmcnt(N) partial drains.
    HSUMT(0, x0, y0);
    HSUMT(1, x1, y1);
    HSUMT(2, x2, y2);  EMIT(h0 + 0);
    HSUMT(0, x3, y3);  EMIT(h0 + 1);
    HSUMT(1, x4, y4);  EMIT(h0 + 2);
    HSUMT(2, x5, y5);  EMIT(h0 + 3);
    HSUMT(0, x6, y6);  EMIT(h0 + 4);
    HSUMT(1, x7, y7);  EMIT(h0 + 5);
#undef LOADR
#undef HSUMT
#undef EMIT
}

__global__ __launch_bounds__(BW * WAVES) void ssim_kernel(
    const float* __restrict__ x, const float* __restrict__ y,
    float* __restrict__ out)
{
    const int tc = blockIdx.x * BW + threadIdx.x;   // 0..319
    const int c0 = tc * VEC;                        // 0..638
    const int h0 = (blockIdx.y * WAVES + threadIdx.y) * KROWS;
    const size_t pbase = (size_t)blockIdx.z * (size_t)(HH * WW);

    const bool ledge = (c0 == 0);
    const bool redge = (c0 == WW - VEC);

    // image-edge lanes exist only in the first and last x-blocks;
    // wave-uniform scalar branch -> interior blocks run the select-free clone
    if (blockIdx.x == 0 || blockIdx.x == gridDim.x - 1)
        ssim_body<true >(x + pbase, y + pbase, out + pbase, c0, h0, ledge, redge);
    else
        ssim_body<false>(x + pbase, y + pbase, out + pbase, c0, h0, ledge, redge);
}

extern "C" void kernel_launch(void* const* d_in, const int* in_sizes, int n_in,
                              void* d_out, int out_size, void* d_ws, size_t ws_size,
                              hipStream_t stream) {
    const float* x = (const float*)d_in[0];
    const float* y = (const float*)d_in[1];
    float* out = (float*)d_out;

    const int planes = in_sizes[0] / (HH * WW);                // 32*3 = 96
    dim3 grid(TCOLS / BW, HH / (KROWS * WAVES), planes);       // (5, 32, 96)
    dim3 block(BW, WAVES);
    ssim_kernel<<<grid, block, 0, stream>>>(x, y, out);
}